// Round 7
// baseline (4022.269 us; speedup 1.0000x reference)
//
#include <hip/hip_runtime.h>

// MM_LSTM_Age_v2 on MI355X — single fused systolic pipeline.
// Round 7: R6 (RE/RS=12, 3681us) + CROSS-STEP GATHER PREFETCH in the pacing
// stages. Deep rings mean next step's inter-stage data (eco h for rec1,
// hs rings for rec2) is already published mid-step; issue those loads right
// after the current gather is consumed (register reuse, no extra VGPR) and
// let them service under the MFMA/fusion phases. Tag poll at use time is
// unchanged -> identical correctness, retries only when truly not ready.
// k0a/k0b: weight transpose->bf16.  k1: eco xW (full T).
// kP (240 WGs, 1 block/CU): rec0(16) + rec1(112) + rec2(112), tag-embedded
//   u64 exchange words {state(hi32), 2xbf16(lo32)}, relaxed agent atomics.
//   Flags (hDf/h2f) as lagged ring-overwrite guards (distance RE/RS).
// k7/k8: dense head.

#define TT 365
#define RE 12  // eco h ring slots
#define RS 12  // hs (data/att -> ts) ring slots

typedef short bf16x8 __attribute__((ext_vector_type(8)));
typedef float f32x4 __attribute__((ext_vector_type(4)));

__device__ __forceinline__ float b2f(unsigned short u) {
  union { unsigned u32; float f; } v; v.u32 = ((unsigned)u) << 16; return v.f;
}
__device__ __forceinline__ unsigned short f2b(float f) {
  union { float f; unsigned u32; } v; v.f = f;
  unsigned u = v.u32;
  u = u + 0x7FFFu + ((u >> 16) & 1u);   // RNE
  return (unsigned short)(u >> 16);
}
__device__ __forceinline__ float sigf(float x) { return 1.0f / (1.0f + __expf(-x)); }
__device__ __forceinline__ float tanh_(float x) { return 2.0f / (1.0f + __expf(-2.0f * x)) - 1.0f; }

__device__ __forceinline__ unsigned long long ld64(const unsigned long long* p) {
  return __hip_atomic_load(p, __ATOMIC_RELAXED, __HIP_MEMORY_SCOPE_AGENT);
}
__device__ __forceinline__ void st64(unsigned long long* p, unsigned long long v) {
  __hip_atomic_store(p, v, __ATOMIC_RELAXED, __HIP_MEMORY_SCOPE_AGENT);
}
__device__ __forceinline__ unsigned ld32(const unsigned* p) {
  return __hip_atomic_load(p, __ATOMIC_RELAXED, __HIP_MEMORY_SCOPE_AGENT);
}
__device__ __forceinline__ void st32(unsigned* p, unsigned v) {
  __hip_atomic_store(p, v, __ATOMIC_RELAXED, __HIP_MEMORY_SCOPE_AGENT);
}
__device__ __forceinline__ unsigned long long tag2(unsigned tag, float a, float b) {
  return ((unsigned long long)tag << 32) | (unsigned)f2b(a) | ((unsigned)f2b(b) << 16);
}

// ------------------------------------------------ k0a: Wr transpose -> bf16
// wr_swz per (lstm,wg): [kb 8][col 128][ks 32], col = gate*32+hi
__global__ __launch_bounds__(256) void k0a_wr(const float* __restrict__ eco_Wr,
    const float* __restrict__ data_Wr, const float* __restrict__ att_Wr,
    const float* __restrict__ ts_Wr, unsigned short* __restrict__ wr_swz)
{
  __shared__ float ls[32 * 133];
  const int kb = blockIdx.x, wg = blockIdx.y, l = blockIdx.z, tid = threadIdx.x;
  const float* src;
  if (l == 0) src = eco_Wr;
  else if (l < 15) { int d = l - 1; src = ((d & 1) ? att_Wr : data_Wr) + (size_t)(d >> 1) * 262144; }
  else src = ts_Wr + (size_t)(l - 15) * 262144;
  for (int e = tid; e < 4096; e += 256) {
    int ks = e >> 7, col = e & 127;
    int gate = col >> 5, hi = col & 31;
    ls[ks * 133 + col] = src[(size_t)(kb * 32 + ks) * 1024 + gate * 256 + wg * 32 + hi];
  }
  __syncthreads();
  unsigned short* out = wr_swz + (((size_t)l * 8 + wg) * 8 + kb) * 4096;
  for (int e = tid; e < 4096; e += 256) {
    int col = e >> 5, ks = e & 31;
    out[e] = f2b(ls[ks * 133 + col]);
  }
}

// ------------------------------------------------ k0b: Wk transpose -> bf16
// wk layout per lstm: [kb 8][col 1024][ks 32] (data/att use K rows 4..259)
__global__ __launch_bounds__(256) void k0b_wk(const float* __restrict__ data_Wk,
    const float* __restrict__ att_Wk, const float* __restrict__ ts_Wk,
    unsigned short* __restrict__ wk_da, unsigned short* __restrict__ wk_ts)
{
  __shared__ float ls[32 * 261];
  const int cc = blockIdx.x, kb = blockIdx.y, d = blockIdx.z, tid = threadIdx.x;
  const float* src; unsigned short* dst; int roff;
  if (d < 14) { src = ((d & 1) ? att_Wk : data_Wk) + (size_t)(d >> 1) * 266240;
                dst = wk_da + (size_t)d * 262144; roff = 4; }
  else { src = ts_Wk + (size_t)(d - 14) * 262144;
         dst = wk_ts + (size_t)(d - 14) * 262144; roff = 0; }
  for (int e = tid; e < 8192; e += 256) {
    int ks = e >> 8, c2 = e & 255;
    ls[ks * 261 + c2] = src[(size_t)(roff + kb * 32 + ks) * 1024 + cc * 256 + c2];
  }
  __syncthreads();
  for (int e = tid; e < 8192; e += 256) {
    int col2 = e >> 5, ks = e & 31;
    dst[(size_t)kb * 32768 + (cc * 256 + col2) * 32 + ks] = f2b(ls[ks * 261 + col2]);
  }
}

// ------------------------------------------------ k1: eco xW full T
__global__ __launch_bounds__(256) void k1_ecoxw(const float* __restrict__ inputs,
    const float* __restrict__ eco_Wk, const float* __restrict__ eco_b,
    unsigned short* __restrict__ xw_eco)
{
  __shared__ float Asl[64 * 35];
  __shared__ float Bsl[35 * 256];
  const int tg = blockIdx.x, ct = blockIdx.y, tid = threadIdx.x;
  for (int i = tid; i < 64 * 35; i += 256) {
    int b = i / 35, k = i - b * 35;
    int col = (k < 20) ? k : (k + 7);
    Asl[i] = inputs[((size_t)b * TT + tg) * 42 + col];
  }
  for (int i = tid; i < 35 * 256; i += 256) {
    int k = i >> 8, c = i & 255;
    Bsl[i] = eco_Wk[(size_t)k * 1024 + ct * 256 + c];
  }
  __syncthreads();
  const float bias = eco_b[ct * 256 + tid];
  for (int r = 0; r < 64; ++r) {
    float s = bias;
    #pragma unroll
    for (int k = 0; k < 35; ++k) s += Asl[r * 35 + k] * Bsl[k * 256 + tid];
    xw_eco[((size_t)tg * 64 + r) * 1024 + ct * 256 + tid] = f2b(s);
  }
}

// ================================================ kP: full systolic pipeline
// hE:  u64[RE][64 row][128 kp]              (eco h, tag = state)
// hD:  per l1 u64[2][64][128]               (data/att own h)
// hsD/hsA: per br u64[RS][64][128]          (hs streams to ts, tag = t+1)
// h2:  per d u64[2][64][128]                (ts own h)
// hDf[112] (l1*8+colwg), h2f[112] (d*16+sub): lagged progress guards.
__global__ __launch_bounds__(256, 1) void kP(
    const unsigned short* __restrict__ wr_swz,
    const unsigned short* __restrict__ wk_da,
    const unsigned short* __restrict__ wk_ts,
    const unsigned short* __restrict__ xw_eco,
    const float* __restrict__ inputs,
    const float* __restrict__ data_Wk, const float* __restrict__ att_Wk,
    const float* __restrict__ data_b, const float* __restrict__ att_b,
    const float* __restrict__ ts_b,
    unsigned long long* __restrict__ hE,
    unsigned long long* __restrict__ hD,
    unsigned long long* __restrict__ hsD,
    unsigned long long* __restrict__ hsA,
    unsigned long long* __restrict__ h2,
    unsigned* __restrict__ hDf, unsigned* __restrict__ h2f,
    float* __restrict__ h_last)
{
  __shared__ __align__(16) unsigned char smem[160256];
  const int tid = threadIdx.x;
  const int widx = blockIdx.x;
  const int lane = tid & 63, w = tid >> 6, c = lane & 15, grp = lane >> 4;

  if (widx < 16) {
    // ================= rec0: eco LSTM, 32 batch x 32 hid per WG
    unsigned short* WR = (unsigned short*)smem;             // 81920
    unsigned short* Hs = (unsigned short*)(smem + 81920);   // 20480
    float* zsh = (float*)(smem + 102400);                   // 16896
    float* cst = (float*)(smem + 119296);                   // 4096
    const int wg = widx >> 1, bg = widx & 1;
    const unsigned short* wr_g = wr_swz + (size_t)wg * 32768;
    for (int i = tid * 8; i < 32768; i += 2048) {
      int kb = i >> 12; int rr = i & 4095; int col = rr >> 5; int ks = rr & 31;
      *(uint4*)&WR[(kb * 128 + col) * 40 + ks] = *(const uint4*)&wr_g[i];
    }
    for (int i = tid; i < 1024; i += 256) cst[i] = 0.0f;

    int xoff[16];
    #pragma unroll
    for (int rt = 0; rt < 2; ++rt)
      #pragma unroll
      for (int ct = 0; ct < 2; ++ct)
        #pragma unroll
        for (int rg = 0; rg < 4; ++rg)
          xoff[(rt * 2 + ct) * 4 + rg] =
              (bg * 32 + rt * 16 + grp * 4 + rg) * 1024 + w * 256 + wg * 32 + ct * 16 + c;
    unsigned short xv[16], xn[16];
    #pragma unroll
    for (int i = 0; i < 16; ++i) xv[i] = xw_eco[xoff[i]];
    __syncthreads();

    for (int t = 0; t < TT; ++t) {
      // lagged ring guard: rec1 must have consumed the slot we overwrite
      if (t + 1 > RE && tid < 112) {
        while ((int)ld32(&hDf[tid]) < t + 1 - RE) __builtin_amdgcn_s_sleep(2);
      }
      { // tag-polled gather of own state t
        const unsigned long long* hb = hE + (size_t)(t % RE) * 8192;
        unsigned long long v[16];
        #pragma unroll
        for (int i = 0; i < 16; ++i) {
          int m = tid + i * 256;
          v[i] = ld64(&hb[(bg * 32 + (m >> 7)) * 128 + (m & 127)]);
        }
        const unsigned tagv = (unsigned)t;
        int tries = 0;
        while (true) {
          unsigned pend = 0u;
          #pragma unroll
          for (int i = 0; i < 16; ++i)
            pend |= ((unsigned)(v[i] >> 32) != tagv) ? (1u << i) : 0u;
          if (!pend) break;
          if (++tries > 8) __builtin_amdgcn_s_sleep(1);
          #pragma unroll
          for (int i = 0; i < 16; ++i)
            if (pend & (1u << i)) {
              int m = tid + i * 256;
              v[i] = ld64(&hb[(bg * 32 + (m >> 7)) * 128 + (m & 127)]);
            }
        }
        #pragma unroll
        for (int i = 0; i < 16; ++i) {
          int m = tid + i * 256, row = m >> 7, kp = m & 127;
          *(unsigned int*)&Hs[((kp >> 4) * 32 + row) * 40 + 2 * (kp & 15)] = (unsigned int)v[i];
        }
      }
      __syncthreads();
      f32x4 acc[4];
      #pragma unroll
      for (int i = 0; i < 4; ++i)
        #pragma unroll
        for (int rg = 0; rg < 4; ++rg) acc[i][rg] = b2f(xv[i * 4 + rg]);
      if (t + 1 < TT) {
        const unsigned short* xw1 = xw_eco + (size_t)(t + 1) * 65536;
        #pragma unroll
        for (int i = 0; i < 16; ++i) xn[i] = xw1[xoff[i]];
      }
      #pragma unroll
      for (int kb = 0; kb < 8; ++kb) {
        bf16x8 a0 = *(const bf16x8*)&Hs[(kb * 32 + c) * 40 + grp * 8];
        bf16x8 a1 = *(const bf16x8*)&Hs[(kb * 32 + 16 + c) * 40 + grp * 8];
        bf16x8 b0 = *(const bf16x8*)&WR[(kb * 128 + w * 32 + c) * 40 + grp * 8];
        bf16x8 b1 = *(const bf16x8*)&WR[(kb * 128 + w * 32 + 16 + c) * 40 + grp * 8];
        acc[0] = __builtin_amdgcn_mfma_f32_16x16x32_bf16(a0, b0, acc[0], 0, 0, 0);
        acc[1] = __builtin_amdgcn_mfma_f32_16x16x32_bf16(a0, b1, acc[1], 0, 0, 0);
        acc[2] = __builtin_amdgcn_mfma_f32_16x16x32_bf16(a1, b0, acc[2], 0, 0, 0);
        acc[3] = __builtin_amdgcn_mfma_f32_16x16x32_bf16(a1, b1, acc[3], 0, 0, 0);
      }
      #pragma unroll
      for (int i = 0; i < 4; ++i) {
        int rt = i >> 1, ct = i & 1;
        #pragma unroll
        for (int rg = 0; rg < 4; ++rg)
          zsh[(rt * 16 + grp * 4 + rg) * 132 + w * 32 + ct * 16 + c] = acc[i][rg];
      }
      __syncthreads();
      { // cell update: 1 row x 4 hid, publish tagged pairs
        int row = tid >> 3, hq8 = tid & 7;
        float4 zi = *(const float4*)&zsh[row * 132 +      hq8 * 4];
        float4 zf = *(const float4*)&zsh[row * 132 + 32 + hq8 * 4];
        float4 zg = *(const float4*)&zsh[row * 132 + 64 + hq8 * 4];
        float4 zo = *(const float4*)&zsh[row * 132 + 96 + hq8 * 4];
        float4 c0 = *(const float4*)&cst[row * 32 + hq8 * 4];
        float cn0 = sigf(zf.x) * c0.x + sigf(zi.x) * tanh_(zg.x);
        float cn1 = sigf(zf.y) * c0.y + sigf(zi.y) * tanh_(zg.y);
        float cn2 = sigf(zf.z) * c0.z + sigf(zi.z) * tanh_(zg.z);
        float cn3 = sigf(zf.w) * c0.w + sigf(zi.w) * tanh_(zg.w);
        float hv0 = sigf(zo.x) * tanh_(cn0);
        float hv1 = sigf(zo.y) * tanh_(cn1);
        float hv2 = sigf(zo.z) * tanh_(cn2);
        float hv3 = sigf(zo.w) * tanh_(cn3);
        *(float4*)&cst[row * 32 + hq8 * 4] = make_float4(cn0, cn1, cn2, cn3);
        unsigned long long* ho = hE + (size_t)((t + 1) % RE) * 8192
                               + (bg * 32 + row) * 128 + wg * 16 + hq8 * 2;
        st64(&ho[0], tag2(t + 1, hv0, hv1));
        st64(&ho[1], tag2(t + 1, hv2, hv3));
      }
      __syncthreads();
      #pragma unroll
      for (int i = 0; i < 16; ++i) xv[i] = xn[i];
    }
  } else if (widx < 128) {
    // ================= rec1: data/att LSTM l1, 64 batch x 32 hid, xW fused
    unsigned short* WR = (unsigned short*)smem;             // 81920
    unsigned short* Hs = (unsigned short*)(smem + 81920);   // 40960
    float* zsh = (float*)(smem + 122880);                   // 33792
    float* a_sp = (float*)(smem + 156672);                  // 1024
    float* b_sp = (float*)(smem + 157696);                  // 2048
    float* bias_s = (float*)(smem + 159744);                // 512
    const int q = widx - 16, l1 = q >> 3, colwg = q & 7, br = l1 >> 1;
    const bool act_sig = (l1 & 1);
    const unsigned short* wr_g = wr_swz + ((size_t)(1 + l1) * 8 + colwg) * 32768;
    for (int i = tid * 8; i < 32768; i += 2048) {
      int kb = i >> 12; int rr = i & 4095; int col = rr >> 5; int ks = rr & 31;
      *(uint4*)&WR[(kb * 128 + col) * 40 + ks] = *(const uint4*)&wr_g[i];
    }
    bf16x8 wkf[16];
    const unsigned short* wk = wk_da + (size_t)l1 * 262144;
    #pragma unroll
    for (int kb = 0; kb < 8; ++kb)
      #pragma unroll
      for (int ct = 0; ct < 2; ++ct) {
        int col = w * 256 + colwg * 32 + ct * 16 + c;
        wkf[kb * 2 + ct] = *(const bf16x8*)&wk[kb * 32768 + col * 32 + grp * 8];
      }
    const float* spWk = (act_sig ? att_Wk : data_Wk) + (size_t)br * 266240;
    for (int i = tid; i < 512; i += 256) {
      int j = i >> 7, colL = i & 127;
      int gcol = (colL >> 5) * 256 + colwg * 32 + (colL & 31);
      b_sp[i] = spWk[(size_t)j * 1024 + gcol];
    }
    if (tid < 128) {
      int gcol = (tid >> 5) * 256 + colwg * 32 + (tid & 31);
      bias_s[tid] = (act_sig ? att_b : data_b)[br * 1024 + gcol];
    }
    float creg[8];
    #pragma unroll
    for (int j = 0; j < 8; ++j) creg[j] = 0.0f;
    unsigned long long* hDl = hD + (size_t)l1 * 2 * 8192;
    unsigned long long* ring = (act_sig ? hsA : hsD) + (size_t)br * RS * 8192;
    unsigned long long ve[32], vh[32];
    __syncthreads();
    { // initial eco gather issue for t=0 (tag 1, slot 1%RE)
      const unsigned long long* he0 = hE + (size_t)(1 % RE) * 8192;
      #pragma unroll
      for (int i = 0; i < 32; ++i) ve[i] = ld64(&he0[tid + i * 256]);
    }

    for (int t = 0; t < TT; ++t) {
      // lagged ring guard: rec2 must have consumed the hs slot we overwrite
      if (t + 1 > RS && tid < 16) {
        while ((int)ld32(&h2f[br * 16 + tid]) < t + 1 - RS) __builtin_amdgcn_s_sleep(2);
      }
      if (tid < 64) {
        const float* ip = inputs + ((size_t)tid * TT + t) * 42;
        a_sp[tid * 4 + 0] = ip[20 + br];
        a_sp[tid * 4 + 1] = ip[27];
        a_sp[tid * 4 + 2] = ip[27 + br + 1];
        a_sp[tid * 4 + 3] = ip[27 + br + 8];
      }
      const unsigned long long* he = hE + (size_t)((t + 1) % RE) * 8192;
      const unsigned long long* ho = hDl + (size_t)(t & 1) * 8192;
      #pragma unroll
      for (int i = 0; i < 32; ++i) vh[i] = ld64(&ho[tid + i * 256]);
      { // poll eco h tags == t+1 (ve prefetched during prior step)
        const unsigned tagv = (unsigned)(t + 1);
        int tries = 0;
        while (true) {
          unsigned long long pend = 0ull;
          #pragma unroll
          for (int i = 0; i < 32; ++i)
            pend |= ((unsigned)(ve[i] >> 32) != tagv) ? (1ull << i) : 0ull;
          if (!pend) break;
          if (++tries > 8) __builtin_amdgcn_s_sleep(1);
          #pragma unroll
          for (int i = 0; i < 32; ++i)
            if (pend & (1ull << i)) ve[i] = ld64(&he[tid + i * 256]);
        }
      }
      #pragma unroll
      for (int i = 0; i < 32; ++i) {
        int m = tid + i * 256, row = m >> 7, kp = m & 127;
        *(unsigned int*)&Hs[((kp >> 4) * 64 + row) * 40 + 2 * (kp & 15)] = (unsigned int)ve[i];
      }
      __syncthreads();
      // PREFETCH next step's eco h (tag t+2; rec0 runs up to RE=12 ahead)
      // into the now-free ve registers; services under xW/recurrent MFMA.
      if (t + 1 < TT) {
        const unsigned long long* hen = hE + (size_t)((t + 2) % RE) * 8192;
        #pragma unroll
        for (int i = 0; i < 32; ++i) ve[i] = ld64(&hen[tid + i * 256]);
      }
      // xW MFMA (A = eco h, B = Wk regs)
      f32x4 acc[8] = {};
      #pragma unroll
      for (int kb = 0; kb < 8; ++kb) {
        bf16x8 a[4];
        #pragma unroll
        for (int rt = 0; rt < 4; ++rt)
          a[rt] = *(const bf16x8*)&Hs[(kb * 64 + rt * 16 + c) * 40 + grp * 8];
        #pragma unroll
        for (int rt = 0; rt < 4; ++rt)
          #pragma unroll
          for (int ct = 0; ct < 2; ++ct)
            acc[rt * 2 + ct] = __builtin_amdgcn_mfma_f32_16x16x32_bf16(a[rt], wkf[kb * 2 + ct], acc[rt * 2 + ct], 0, 0, 0);
      }
      #pragma unroll
      for (int i = 0; i < 8; ++i) {
        int rt = i >> 1, ct2 = i & 1;
        #pragma unroll
        for (int rg = 0; rg < 4; ++rg) {
          int row = rt * 16 + grp * 4 + rg;
          int colL = w * 32 + ct2 * 16 + c;
          acc[i][rg] += bias_s[colL]
                      + a_sp[row * 4 + 0] * b_sp[colL]       + a_sp[row * 4 + 1] * b_sp[128 + colL]
                      + a_sp[row * 4 + 2] * b_sp[256 + colL] + a_sp[row * 4 + 3] * b_sp[384 + colL];
        }
      }
      { // poll own h tags == t (usually instant)
        const unsigned tagv = (unsigned)t;
        int tries = 0;
        while (true) {
          unsigned long long pend = 0ull;
          #pragma unroll
          for (int i = 0; i < 32; ++i)
            pend |= ((unsigned)(vh[i] >> 32) != tagv) ? (1ull << i) : 0ull;
          if (!pend) break;
          if (++tries > 8) __builtin_amdgcn_s_sleep(1);
          #pragma unroll
          for (int i = 0; i < 32; ++i)
            if (pend & (1ull << i)) vh[i] = ld64(&ho[tid + i * 256]);
        }
      }
      __syncthreads();                 // everyone done reading Hs (eco h)
      #pragma unroll
      for (int i = 0; i < 32; ++i) {
        int m = tid + i * 256, row = m >> 7, kp = m & 127;
        *(unsigned int*)&Hs[((kp >> 4) * 64 + row) * 40 + 2 * (kp & 15)] = (unsigned int)vh[i];
      }
      __syncthreads();
      // recurrent MFMA (A = own h, B = Wr LDS)
      #pragma unroll
      for (int kb = 0; kb < 8; ++kb) {
        bf16x8 a[4]; bf16x8 b[2];
        #pragma unroll
        for (int rt = 0; rt < 4; ++rt)
          a[rt] = *(const bf16x8*)&Hs[(kb * 64 + rt * 16 + c) * 40 + grp * 8];
        #pragma unroll
        for (int ct = 0; ct < 2; ++ct)
          b[ct] = *(const bf16x8*)&WR[(kb * 128 + w * 32 + ct * 16 + c) * 40 + grp * 8];
        #pragma unroll
        for (int rt = 0; rt < 4; ++rt)
          #pragma unroll
          for (int ct = 0; ct < 2; ++ct)
            acc[rt * 2 + ct] = __builtin_amdgcn_mfma_f32_16x16x32_bf16(a[rt], b[ct], acc[rt * 2 + ct], 0, 0, 0);
      }
      #pragma unroll
      for (int i = 0; i < 8; ++i) {
        int rt = i >> 1, ct2 = i & 1;
        #pragma unroll
        for (int rg = 0; rg < 4; ++rg)
          zsh[(rt * 16 + grp * 4 + rg) * 132 + w * 32 + ct2 * 16 + c] = acc[i][rg];
      }
      __syncthreads();
      { // cell: 2 items x 4 hid; publish own h (2-slot) + hs ring (tag t+1)
        unsigned long long* hon = hDl + (size_t)((t + 1) & 1) * 8192;
        unsigned long long* rs = ring + (size_t)(t % RS) * 8192;
        #pragma unroll
        for (int it = 0; it < 2; ++it) {
          int m = tid + it * 256, row = m >> 3, hq8 = m & 7;
          float4 zi = *(const float4*)&zsh[row * 132 +      hq8 * 4];
          float4 zf = *(const float4*)&zsh[row * 132 + 32 + hq8 * 4];
          float4 zg = *(const float4*)&zsh[row * 132 + 64 + hq8 * 4];
          float4 zo = *(const float4*)&zsh[row * 132 + 96 + hq8 * 4];
          float g0 = act_sig ? sigf(zg.x) : tanh_(zg.x);
          float g1 = act_sig ? sigf(zg.y) : tanh_(zg.y);
          float g2 = act_sig ? sigf(zg.z) : tanh_(zg.z);
          float g3 = act_sig ? sigf(zg.w) : tanh_(zg.w);
          float cn0 = sigf(zf.x) * creg[it * 4 + 0] + sigf(zi.x) * g0;
          float cn1 = sigf(zf.y) * creg[it * 4 + 1] + sigf(zi.y) * g1;
          float cn2 = sigf(zf.z) * creg[it * 4 + 2] + sigf(zi.z) * g2;
          float cn3 = sigf(zf.w) * creg[it * 4 + 3] + sigf(zi.w) * g3;
          float hv0 = sigf(zo.x) * (act_sig ? sigf(cn0) : tanh_(cn0));
          float hv1 = sigf(zo.y) * (act_sig ? sigf(cn1) : tanh_(cn1));
          float hv2 = sigf(zo.z) * (act_sig ? sigf(cn2) : tanh_(cn2));
          float hv3 = sigf(zo.w) * (act_sig ? sigf(cn3) : tanh_(cn3));
          creg[it * 4 + 0] = cn0; creg[it * 4 + 1] = cn1;
          creg[it * 4 + 2] = cn2; creg[it * 4 + 3] = cn3;
          int kp = colwg * 16 + hq8 * 2;
          unsigned long long w0 = tag2(t + 1, hv0, hv1);
          unsigned long long w1 = tag2(t + 1, hv2, hv3);
          st64(&hon[row * 128 + kp], w0);
          st64(&hon[row * 128 + kp + 1], w1);
          st64(&rs[row * 128 + kp], w0);
          st64(&rs[row * 128 + kp + 1], w1);
        }
      }
      __builtin_amdgcn_s_waitcnt(0);
      __syncthreads();
      if (tid == 0) st32(&hDf[q], (unsigned)(t + 1));   // lagged guard only
    }
  } else {
    // ================= rec2: ts LSTM d, 32 batch x 32 hid, xW fused
    unsigned short* WR = (unsigned short*)smem;             // 81920
    unsigned short* Hs = (unsigned short*)(smem + 81920);   // 20480
    float* zsh = (float*)(smem + 102400);                   // 16896
    float* bias_s = (float*)(smem + 119296);                // 512
    const int r = widx - 128, d = r >> 4, sub = r & 15, colwg = sub >> 1, bg = sub & 1;
    const unsigned short* wr_g = wr_swz + ((size_t)(15 + d) * 8 + colwg) * 32768;
    for (int i = tid * 8; i < 32768; i += 2048) {
      int kb = i >> 12; int rr = i & 4095; int col = rr >> 5; int ks = rr & 31;
      *(uint4*)&WR[(kb * 128 + col) * 40 + ks] = *(const uint4*)&wr_g[i];
    }
    bf16x8 wkf[16];
    const unsigned short* wk = wk_ts + (size_t)d * 262144;
    #pragma unroll
    for (int kb = 0; kb < 8; ++kb)
      #pragma unroll
      for (int ct = 0; ct < 2; ++ct) {
        int col = w * 256 + colwg * 32 + ct * 16 + c;
        wkf[kb * 2 + ct] = *(const bf16x8*)&wk[kb * 32768 + col * 32 + grp * 8];
      }
    if (tid < 128) {
      int gcol = (tid >> 5) * 256 + colwg * 32 + (tid & 31);
      bias_s[tid] = ts_b[d * 1024 + gcol];
    }
    float creg[4] = {0.0f, 0.0f, 0.0f, 0.0f};
    const unsigned long long* rD = hsD + (size_t)d * RS * 8192;
    const unsigned long long* rA = hsA + (size_t)d * RS * 8192;
    unsigned long long* h2d = h2 + (size_t)d * 2 * 8192;
    int idx16[16];
    #pragma unroll
    for (int i = 0; i < 16; ++i) {
      int m = tid + i * 256;
      idx16[i] = (bg * 32 + (m >> 7)) * 128 + (m & 127);
    }
    unsigned long long vd[16], va[16], vh[16];
    __syncthreads();
    { // initial hs gather issue for t=0 (slot 0, tag 1)
      #pragma unroll
      for (int i = 0; i < 16; ++i) vd[i] = ld64(&rD[idx16[i]]);
      #pragma unroll
      for (int i = 0; i < 16; ++i) va[i] = ld64(&rA[idx16[i]]);
    }

    for (int t = 0; t < TT; ++t) {
      const unsigned long long* sd = rD + (size_t)(t % RS) * 8192;
      const unsigned long long* sa = rA + (size_t)(t % RS) * 8192;
      const unsigned long long* ho = h2d + (size_t)(t & 1) * 8192;
      #pragma unroll
      for (int i = 0; i < 16; ++i) vh[i] = ld64(&ho[idx16[i]]);
      { // poll hs tags == t+1 (vd/va prefetched during prior step)
        const unsigned tagv = (unsigned)(t + 1);
        int tries = 0;
        while (true) {
          unsigned pend = 0u;
          #pragma unroll
          for (int i = 0; i < 16; ++i) {
            pend |= ((unsigned)(vd[i] >> 32) != tagv) ? (1u << i) : 0u;
            pend |= ((unsigned)(va[i] >> 32) != tagv) ? (0x10000u << i) : 0u;
          }
          if (!pend) break;
          if (++tries > 8) __builtin_amdgcn_s_sleep(1);
          #pragma unroll
          for (int i = 0; i < 16; ++i) {
            if (pend & (1u << i)) vd[i] = ld64(&sd[idx16[i]]);
            if (pend & (0x10000u << i)) va[i] = ld64(&sa[idx16[i]]);
          }
        }
      }
      #pragma unroll
      for (int i = 0; i < 16; ++i) {  // product -> Hs
        int m = tid + i * 256, row = m >> 7, kp = m & 127;
        unsigned dl = (unsigned)vd[i], al = (unsigned)va[i];
        float p0 = b2f((unsigned short)dl) * b2f((unsigned short)al);
        float p1 = b2f((unsigned short)(dl >> 16)) * b2f((unsigned short)(al >> 16));
        unsigned pv = (unsigned)f2b(p0) | ((unsigned)f2b(p1) << 16);
        *(unsigned int*)&Hs[((kp >> 4) * 32 + row) * 40 + 2 * (kp & 15)] = pv;
      }
      __syncthreads();
      // PREFETCH next step's hs (tag t+2) into freed vd/va registers;
      // hits whenever rec2 trails rec1 by >=1 step (steady state), else
      // the use-time poll retries exactly as before.
      if (t + 1 < TT) {
        const unsigned long long* sdn = rD + (size_t)((t + 1) % RS) * 8192;
        const unsigned long long* san = rA + (size_t)((t + 1) % RS) * 8192;
        #pragma unroll
        for (int i = 0; i < 16; ++i) vd[i] = ld64(&sdn[idx16[i]]);
        #pragma unroll
        for (int i = 0; i < 16; ++i) va[i] = ld64(&san[idx16[i]]);
      }
      f32x4 acc[4] = {};
      #pragma unroll
      for (int kb = 0; kb < 8; ++kb) {
        bf16x8 a0 = *(const bf16x8*)&Hs[(kb * 32 + c) * 40 + grp * 8];
        bf16x8 a1 = *(const bf16x8*)&Hs[(kb * 32 + 16 + c) * 40 + grp * 8];
        acc[0] = __builtin_amdgcn_mfma_f32_16x16x32_bf16(a0, wkf[kb * 2 + 0], acc[0], 0, 0, 0);
        acc[1] = __builtin_amdgcn_mfma_f32_16x16x32_bf16(a0, wkf[kb * 2 + 1], acc[1], 0, 0, 0);
        acc[2] = __builtin_amdgcn_mfma_f32_16x16x32_bf16(a1, wkf[kb * 2 + 0], acc[2], 0, 0, 0);
        acc[3] = __builtin_amdgcn_mfma_f32_16x16x32_bf16(a1, wkf[kb * 2 + 1], acc[3], 0, 0, 0);
      }
      #pragma unroll
      for (int i = 0; i < 4; ++i) {
        int ct2 = i & 1;
        #pragma unroll
        for (int rg = 0; rg < 4; ++rg)
          acc[i][rg] += bias_s[w * 32 + ct2 * 16 + c];
      }
      { // poll own h tags == t (instant)
        const unsigned tagv = (unsigned)t;
        int tries = 0;
        while (true) {
          unsigned pend = 0u;
          #pragma unroll
          for (int i = 0; i < 16; ++i)
            pend |= ((unsigned)(vh[i] >> 32) != tagv) ? (1u << i) : 0u;
          if (!pend) break;
          if (++tries > 8) __builtin_amdgcn_s_sleep(1);
          #pragma unroll
          for (int i = 0; i < 16; ++i)
            if (pend & (1u << i)) vh[i] = ld64(&ho[idx16[i]]);
        }
      }
      __syncthreads();
      #pragma unroll
      for (int i = 0; i < 16; ++i) {
        int m = tid + i * 256, row = m >> 7, kp = m & 127;
        *(unsigned int*)&Hs[((kp >> 4) * 32 + row) * 40 + 2 * (kp & 15)] = (unsigned int)vh[i];
      }
      __syncthreads();
      #pragma unroll
      for (int kb = 0; kb < 8; ++kb) {
        bf16x8 a0 = *(const bf16x8*)&Hs[(kb * 32 + c) * 40 + grp * 8];
        bf16x8 a1 = *(const bf16x8*)&Hs[(kb * 32 + 16 + c) * 40 + grp * 8];
        bf16x8 b0 = *(const bf16x8*)&WR[(kb * 128 + w * 32 + c) * 40 + grp * 8];
        bf16x8 b1 = *(const bf16x8*)&WR[(kb * 128 + w * 32 + 16 + c) * 40 + grp * 8];
        acc[0] = __builtin_amdgcn_mfma_f32_16x16x32_bf16(a0, b0, acc[0], 0, 0, 0);
        acc[1] = __builtin_amdgcn_mfma_f32_16x16x32_bf16(a0, b1, acc[1], 0, 0, 0);
        acc[2] = __builtin_amdgcn_mfma_f32_16x16x32_bf16(a1, b0, acc[2], 0, 0, 0);
        acc[3] = __builtin_amdgcn_mfma_f32_16x16x32_bf16(a1, b1, acc[3], 0, 0, 0);
      }
      #pragma unroll
      for (int i = 0; i < 4; ++i) {
        int rt = i >> 1, ct2 = i & 1;
        #pragma unroll
        for (int rg = 0; rg < 4; ++rg)
          zsh[(rt * 16 + grp * 4 + rg) * 132 + w * 32 + ct2 * 16 + c] = acc[i][rg];
      }
      __syncthreads();
      { // cell: 1 row x 4 hid; publish h2 (2-slot)
        int row = tid >> 3, hq8 = tid & 7;
        float4 zi = *(const float4*)&zsh[row * 132 +      hq8 * 4];
        float4 zf = *(const float4*)&zsh[row * 132 + 32 + hq8 * 4];
        float4 zg = *(const float4*)&zsh[row * 132 + 64 + hq8 * 4];
        float4 zo = *(const float4*)&zsh[row * 132 + 96 + hq8 * 4];
        float cn0 = sigf(zf.x) * creg[0] + sigf(zi.x) * tanh_(zg.x);
        float cn1 = sigf(zf.y) * creg[1] + sigf(zi.y) * tanh_(zg.y);
        float cn2 = sigf(zf.z) * creg[2] + sigf(zi.z) * tanh_(zg.z);
        float cn3 = sigf(zf.w) * creg[3] + sigf(zi.w) * tanh_(zg.w);
        float hv0 = sigf(zo.x) * tanh_(cn0);
        float hv1 = sigf(zo.y) * tanh_(cn1);
        float hv2 = sigf(zo.z) * tanh_(cn2);
        float hv3 = sigf(zo.w) * tanh_(cn3);
        creg[0] = cn0; creg[1] = cn1; creg[2] = cn2; creg[3] = cn3;
        unsigned long long* hn = h2d + (size_t)((t + 1) & 1) * 8192
                               + (bg * 32 + row) * 128 + colwg * 16 + hq8 * 2;
        st64(&hn[0], tag2(t + 1, hv0, hv1));
        st64(&hn[1], tag2(t + 1, hv2, hv3));
        if (t == TT - 1) {
          *(float4*)&h_last[(size_t)d * 16384 + (bg * 32 + row) * 256 + colwg * 32 + hq8 * 4]
              = make_float4(hv0, hv1, hv2, hv3);
        }
      }
      __builtin_amdgcn_s_waitcnt(0);
      __syncthreads();
      if (tid == 0) st32(&h2f[d * 16 + sub], (unsigned)(t + 1));   // lagged guard
    }
  }
}

// ------------------------------------------------ head
__global__ __launch_bounds__(256) void k7_d1(const float* __restrict__ h_last,
    const float* __restrict__ d1_W, const float* __restrict__ d1_b, float* __restrict__ d1o)
{
  __shared__ float Asl[64 * 256];
  __shared__ float Bsl[256 * 64];
  const int nt = blockIdx.x, br = blockIdx.y, tid = threadIdx.x;
  const float* hl = h_last + (size_t)br * 16384;
  for (int i = tid; i < 16384; i += 256) Asl[i] = hl[i];
  const float* wp = d1_W + (size_t)br * 65536 + nt * 64;
  for (int i = tid; i < 16384; i += 256) {
    int k = i >> 6, cl = i & 63;
    Bsl[i] = wp[(size_t)k * 256 + cl];
  }
  __syncthreads();
  const int cl = tid & 63, rq = tid >> 6;
  float s[16];
  const float bias = d1_b[br * 256 + nt * 64 + cl];
  #pragma unroll
  for (int i = 0; i < 16; ++i) s[i] = bias;
  for (int k = 0; k < 256; ++k) {
    float bv = Bsl[k * 64 + cl];
    #pragma unroll
    for (int i = 0; i < 16; ++i) s[i] += Asl[(rq * 16 + i) * 256 + k] * bv;
  }
  #pragma unroll
  for (int i = 0; i < 16; ++i)
    d1o[(size_t)br * 16384 + (rq * 16 + i) * 256 + nt * 64 + cl] = fmaxf(s[i], 0.0f);
}

__global__ __launch_bounds__(256) void k8_head(const float* __restrict__ d1o,
    const float* __restrict__ d2_W, const float* __restrict__ d2_b,
    const float* __restrict__ df_W, const float* __restrict__ df_b,
    const float* __restrict__ inputs, float* __restrict__ out)
{
  __shared__ float Asl[64 * 256];
  __shared__ float Bsl[256 * 64];
  __shared__ float d2sT[64 * 65];
  __shared__ float wfs[68];
  const int br = blockIdx.x, tid = threadIdx.x;
  for (int i = tid; i < 16384; i += 256) Asl[i] = d1o[(size_t)br * 16384 + i];
  for (int i = tid; i < 16384; i += 256) Bsl[i] = d2_W[(size_t)br * 16384 + i];
  if (tid < 67) wfs[tid] = df_W[br * 67 + tid];
  __syncthreads();
  const int cl = tid & 63, rq = tid >> 6;
  float s[16];
  const float bias = d2_b[br * 64 + cl];
  #pragma unroll
  for (int i = 0; i < 16; ++i) s[i] = bias;
  for (int k = 0; k < 256; ++k) {
    float bv = Bsl[k * 64 + cl];
    #pragma unroll
    for (int i = 0; i < 16; ++i) s[i] += Asl[(rq * 16 + i) * 256 + k] * bv;
  }
  #pragma unroll
  for (int i = 0; i < 16; ++i) d2sT[cl * 65 + rq * 16 + i] = fmaxf(s[i], 0.0f);
  __syncthreads();
  if (tid < 64) {
    const int b = tid;
    const float* ip = inputs + ((size_t)b * TT + (TT - 1)) * 42;
    float acc = df_b[br] + ip[20 + br] + ip[27] * wfs[64] + ip[27 + br + 1] * wfs[65]
              + ip[27 + br + 8] * wfs[66];
    #pragma unroll 4
    for (int j = 0; j < 64; ++j) acc += d2sT[j * 65 + b] * wfs[j];
    out[b * 7 + br] = acc;
  }
}

// ------------------------------------------------ host
extern "C" void kernel_launch(void* const* d_in, const int* in_sizes, int n_in,
                              void* d_out, int out_size, void* d_ws, size_t ws_size,
                              hipStream_t stream) {
  (void)in_sizes; (void)n_in; (void)out_size;
  const float* inputs  = (const float*)d_in[0];
  const float* eco_Wk  = (const float*)d_in[1];
  const float* eco_Wr  = (const float*)d_in[2];
  const float* eco_b   = (const float*)d_in[3];
  const float* data_Wk = (const float*)d_in[4];
  const float* data_Wr = (const float*)d_in[5];
  const float* data_b  = (const float*)d_in[6];
  const float* att_Wk  = (const float*)d_in[7];
  const float* att_Wr  = (const float*)d_in[8];
  const float* att_b   = (const float*)d_in[9];
  const float* ts_Wk   = (const float*)d_in[10];
  const float* ts_Wr   = (const float*)d_in[11];
  const float* ts_b    = (const float*)d_in[12];
  const float* d1_W    = (const float*)d_in[13];
  const float* d1_b    = (const float*)d_in[14];
  const float* d2_W    = (const float*)d_in[15];
  const float* d2_b    = (const float*)d_in[16];
  const float* df_W    = (const float*)d_in[17];
  const float* df_b    = (const float*)d_in[18];

  char* ws = (char*)d_ws;
  size_t off = 0;
  auto take = [&](size_t bytes) -> void* {
    void* p = ws + off;
    off += (bytes + 255) & ~(size_t)255;
    return p;
  };
  unsigned short* wr_swz = (unsigned short*)take((size_t)22 * 262144 * 2);
  unsigned short* wk_da  = (unsigned short*)take((size_t)14 * 262144 * 2);
  unsigned short* wk_ts  = (unsigned short*)take((size_t)7  * 262144 * 2);
  unsigned short* xw_eco = (unsigned short*)take((size_t)TT * 65536 * 2);
  float*          h_last = (float*)take((size_t)7 * 16384 * 4);
  float*          d1o    = (float*)take((size_t)7 * 16384 * 4);
  // --- sync region (contiguous, memset each launch) ---
  size_t sync_begin = off;
  unsigned long long* hE  = (unsigned long long*)take((size_t)RE * 8192 * 8);
  unsigned long long* hD  = (unsigned long long*)take((size_t)14 * 2 * 8192 * 8);
  unsigned long long* hsD = (unsigned long long*)take((size_t)7 * RS * 8192 * 8);
  unsigned long long* hsA = (unsigned long long*)take((size_t)7 * RS * 8192 * 8);
  unsigned long long* h2  = (unsigned long long*)take((size_t)7 * 2 * 8192 * 8);
  unsigned* hDf = (unsigned*)take(112 * 4);
  unsigned* h2f = (unsigned*)take(112 * 4);
  size_t sync_bytes = off - sync_begin;
  if (off > ws_size) return;   // fail loudly (output stays zero)

  hipMemsetAsync(ws + sync_begin, 0, sync_bytes, stream);
  k0a_wr<<<dim3(8, 8, 22), 256, 0, stream>>>(eco_Wr, data_Wr, att_Wr, ts_Wr, wr_swz);
  k0b_wk<<<dim3(4, 8, 21), 256, 0, stream>>>(data_Wk, att_Wk, ts_Wk, wk_da, wk_ts);
  k1_ecoxw<<<dim3(TT, 4), 256, 0, stream>>>(inputs, eco_Wk, eco_b, xw_eco);
  kP<<<240, 256, 0, stream>>>(wr_swz, wk_da, wk_ts, xw_eco, inputs,
                              data_Wk, att_Wk, data_b, att_b, ts_b,
                              hE, hD, hsD, hsA, h2, hDf, h2f, h_last);
  k7_d1<<<dim3(4, 7), 256, 0, stream>>>(h_last, d1_W, d1_b, d1o);
  k8_head<<<7, 256, 0, stream>>>(d1o, d2_W, d2_b, df_W, df_b, inputs, (float*)d_out);
}

// Round 8
// 3752.739 us; speedup vs baseline: 1.0718x; 1.0718x over previous
//
#include <hip/hip_runtime.h>

// MM_LSTM_Age_v2 on MI355X — single fused systolic pipeline.
// Round 8: R6 (RE/RS=12, best 3681us) with the end-of-step STORE DRAIN
// (s_waitcnt vmcnt(0)) + trailing barrier REMOVED in all three stages.
// The drain only stalls the wave (~1-2k cy) — it does not speed store
// visibility; flags (hDf/h2f) assert ring-slot CONSUMPTION (done at the
// step's first barrier), not publish completion; all publish reads are
// tag-guarded and self-correcting; LDS hazards are covered by the
// remaining intra-step barriers (audit in round notes).
// k0a/k0b: weight transpose->bf16.  k1: eco xW (full T).
// kP (240 WGs, 1 block/CU): rec0(16) + rec1(112) + rec2(112), tag-embedded
//   u64 exchange words {state(hi32), 2xbf16(lo32)}, relaxed agent atomics.
// k7/k8: dense head.

#define TT 365
#define RE 12  // eco h ring slots
#define RS 12  // hs (data/att -> ts) ring slots

typedef short bf16x8 __attribute__((ext_vector_type(8)));
typedef float f32x4 __attribute__((ext_vector_type(4)));

__device__ __forceinline__ float b2f(unsigned short u) {
  union { unsigned u32; float f; } v; v.u32 = ((unsigned)u) << 16; return v.f;
}
__device__ __forceinline__ unsigned short f2b(float f) {
  union { float f; unsigned u32; } v; v.f = f;
  unsigned u = v.u32;
  u = u + 0x7FFFu + ((u >> 16) & 1u);   // RNE
  return (unsigned short)(u >> 16);
}
__device__ __forceinline__ float sigf(float x) { return 1.0f / (1.0f + __expf(-x)); }
__device__ __forceinline__ float tanh_(float x) { return 2.0f / (1.0f + __expf(-2.0f * x)) - 1.0f; }

__device__ __forceinline__ unsigned long long ld64(const unsigned long long* p) {
  return __hip_atomic_load(p, __ATOMIC_RELAXED, __HIP_MEMORY_SCOPE_AGENT);
}
__device__ __forceinline__ void st64(unsigned long long* p, unsigned long long v) {
  __hip_atomic_store(p, v, __ATOMIC_RELAXED, __HIP_MEMORY_SCOPE_AGENT);
}
__device__ __forceinline__ unsigned ld32(const unsigned* p) {
  return __hip_atomic_load(p, __ATOMIC_RELAXED, __HIP_MEMORY_SCOPE_AGENT);
}
__device__ __forceinline__ void st32(unsigned* p, unsigned v) {
  __hip_atomic_store(p, v, __ATOMIC_RELAXED, __HIP_MEMORY_SCOPE_AGENT);
}
__device__ __forceinline__ unsigned long long tag2(unsigned tag, float a, float b) {
  return ((unsigned long long)tag << 32) | (unsigned)f2b(a) | ((unsigned)f2b(b) << 16);
}

// ------------------------------------------------ k0a: Wr transpose -> bf16
// wr_swz per (lstm,wg): [kb 8][col 128][ks 32], col = gate*32+hi
__global__ __launch_bounds__(256) void k0a_wr(const float* __restrict__ eco_Wr,
    const float* __restrict__ data_Wr, const float* __restrict__ att_Wr,
    const float* __restrict__ ts_Wr, unsigned short* __restrict__ wr_swz)
{
  __shared__ float ls[32 * 133];
  const int kb = blockIdx.x, wg = blockIdx.y, l = blockIdx.z, tid = threadIdx.x;
  const float* src;
  if (l == 0) src = eco_Wr;
  else if (l < 15) { int d = l - 1; src = ((d & 1) ? att_Wr : data_Wr) + (size_t)(d >> 1) * 262144; }
  else src = ts_Wr + (size_t)(l - 15) * 262144;
  for (int e = tid; e < 4096; e += 256) {
    int ks = e >> 7, col = e & 127;
    int gate = col >> 5, hi = col & 31;
    ls[ks * 133 + col] = src[(size_t)(kb * 32 + ks) * 1024 + gate * 256 + wg * 32 + hi];
  }
  __syncthreads();
  unsigned short* out = wr_swz + (((size_t)l * 8 + wg) * 8 + kb) * 4096;
  for (int e = tid; e < 4096; e += 256) {
    int col = e >> 5, ks = e & 31;
    out[e] = f2b(ls[ks * 133 + col]);
  }
}

// ------------------------------------------------ k0b: Wk transpose -> bf16
// wk layout per lstm: [kb 8][col 1024][ks 32] (data/att use K rows 4..259)
__global__ __launch_bounds__(256) void k0b_wk(const float* __restrict__ data_Wk,
    const float* __restrict__ att_Wk, const float* __restrict__ ts_Wk,
    unsigned short* __restrict__ wk_da, unsigned short* __restrict__ wk_ts)
{
  __shared__ float ls[32 * 261];
  const int cc = blockIdx.x, kb = blockIdx.y, d = blockIdx.z, tid = threadIdx.x;
  const float* src; unsigned short* dst; int roff;
  if (d < 14) { src = ((d & 1) ? att_Wk : data_Wk) + (size_t)(d >> 1) * 266240;
                dst = wk_da + (size_t)d * 262144; roff = 4; }
  else { src = ts_Wk + (size_t)(d - 14) * 262144;
         dst = wk_ts + (size_t)(d - 14) * 262144; roff = 0; }
  for (int e = tid; e < 8192; e += 256) {
    int ks = e >> 8, c2 = e & 255;
    ls[ks * 261 + c2] = src[(size_t)(roff + kb * 32 + ks) * 1024 + cc * 256 + c2];
  }
  __syncthreads();
  for (int e = tid; e < 8192; e += 256) {
    int col2 = e >> 5, ks = e & 31;
    dst[(size_t)kb * 32768 + (cc * 256 + col2) * 32 + ks] = f2b(ls[ks * 261 + col2]);
  }
}

// ------------------------------------------------ k1: eco xW full T
__global__ __launch_bounds__(256) void k1_ecoxw(const float* __restrict__ inputs,
    const float* __restrict__ eco_Wk, const float* __restrict__ eco_b,
    unsigned short* __restrict__ xw_eco)
{
  __shared__ float Asl[64 * 35];
  __shared__ float Bsl[35 * 256];
  const int tg = blockIdx.x, ct = blockIdx.y, tid = threadIdx.x;
  for (int i = tid; i < 64 * 35; i += 256) {
    int b = i / 35, k = i - b * 35;
    int col = (k < 20) ? k : (k + 7);
    Asl[i] = inputs[((size_t)b * TT + tg) * 42 + col];
  }
  for (int i = tid; i < 35 * 256; i += 256) {
    int k = i >> 8, c = i & 255;
    Bsl[i] = eco_Wk[(size_t)k * 1024 + ct * 256 + c];
  }
  __syncthreads();
  const float bias = eco_b[ct * 256 + tid];
  for (int r = 0; r < 64; ++r) {
    float s = bias;
    #pragma unroll
    for (int k = 0; k < 35; ++k) s += Asl[r * 35 + k] * Bsl[k * 256 + tid];
    xw_eco[((size_t)tg * 64 + r) * 1024 + ct * 256 + tid] = f2b(s);
  }
}

// ================================================ kP: full systolic pipeline
// hE:  u64[RE][64 row][128 kp]              (eco h, tag = state)
// hD:  per l1 u64[2][64][128]               (data/att own h)
// hsD/hsA: per br u64[RS][64][128]          (hs streams to ts, tag = t+1)
// h2:  per d u64[2][64][128]                (ts own h)
// hDf[112] (l1*8+colwg), h2f[112] (d*16+sub): lagged progress guards.
__global__ __launch_bounds__(256, 1) void kP(
    const unsigned short* __restrict__ wr_swz,
    const unsigned short* __restrict__ wk_da,
    const unsigned short* __restrict__ wk_ts,
    const unsigned short* __restrict__ xw_eco,
    const float* __restrict__ inputs,
    const float* __restrict__ data_Wk, const float* __restrict__ att_Wk,
    const float* __restrict__ data_b, const float* __restrict__ att_b,
    const float* __restrict__ ts_b,
    unsigned long long* __restrict__ hE,
    unsigned long long* __restrict__ hD,
    unsigned long long* __restrict__ hsD,
    unsigned long long* __restrict__ hsA,
    unsigned long long* __restrict__ h2,
    unsigned* __restrict__ hDf, unsigned* __restrict__ h2f,
    float* __restrict__ h_last)
{
  __shared__ __align__(16) unsigned char smem[160256];
  const int tid = threadIdx.x;
  const int widx = blockIdx.x;
  const int lane = tid & 63, w = tid >> 6, c = lane & 15, grp = lane >> 4;

  if (widx < 16) {
    // ================= rec0: eco LSTM, 32 batch x 32 hid per WG
    unsigned short* WR = (unsigned short*)smem;             // 81920
    unsigned short* Hs = (unsigned short*)(smem + 81920);   // 20480
    float* zsh = (float*)(smem + 102400);                   // 16896
    float* cst = (float*)(smem + 119296);                   // 4096
    const int wg = widx >> 1, bg = widx & 1;
    const unsigned short* wr_g = wr_swz + (size_t)wg * 32768;
    for (int i = tid * 8; i < 32768; i += 2048) {
      int kb = i >> 12; int rr = i & 4095; int col = rr >> 5; int ks = rr & 31;
      *(uint4*)&WR[(kb * 128 + col) * 40 + ks] = *(const uint4*)&wr_g[i];
    }
    for (int i = tid; i < 1024; i += 256) cst[i] = 0.0f;

    int xoff[16];
    #pragma unroll
    for (int rt = 0; rt < 2; ++rt)
      #pragma unroll
      for (int ct = 0; ct < 2; ++ct)
        #pragma unroll
        for (int rg = 0; rg < 4; ++rg)
          xoff[(rt * 2 + ct) * 4 + rg] =
              (bg * 32 + rt * 16 + grp * 4 + rg) * 1024 + w * 256 + wg * 32 + ct * 16 + c;
    unsigned short xv[16], xn[16];
    #pragma unroll
    for (int i = 0; i < 16; ++i) xv[i] = xw_eco[xoff[i]];
    __syncthreads();

    for (int t = 0; t < TT; ++t) {
      // lagged ring guard: rec1 must have consumed the slot we overwrite
      if (t + 1 > RE && tid < 112) {
        while ((int)ld32(&hDf[tid]) < t + 1 - RE) __builtin_amdgcn_s_sleep(2);
      }
      { // tag-polled gather of own state t
        const unsigned long long* hb = hE + (size_t)(t % RE) * 8192;
        unsigned long long v[16];
        #pragma unroll
        for (int i = 0; i < 16; ++i) {
          int m = tid + i * 256;
          v[i] = ld64(&hb[(bg * 32 + (m >> 7)) * 128 + (m & 127)]);
        }
        const unsigned tagv = (unsigned)t;
        int tries = 0;
        while (true) {
          unsigned pend = 0u;
          #pragma unroll
          for (int i = 0; i < 16; ++i)
            pend |= ((unsigned)(v[i] >> 32) != tagv) ? (1u << i) : 0u;
          if (!pend) break;
          if (++tries > 8) __builtin_amdgcn_s_sleep(1);
          #pragma unroll
          for (int i = 0; i < 16; ++i)
            if (pend & (1u << i)) {
              int m = tid + i * 256;
              v[i] = ld64(&hb[(bg * 32 + (m >> 7)) * 128 + (m & 127)]);
            }
        }
        #pragma unroll
        for (int i = 0; i < 16; ++i) {
          int m = tid + i * 256, row = m >> 7, kp = m & 127;
          *(unsigned int*)&Hs[((kp >> 4) * 32 + row) * 40 + 2 * (kp & 15)] = (unsigned int)v[i];
        }
      }
      __syncthreads();
      f32x4 acc[4];
      #pragma unroll
      for (int i = 0; i < 4; ++i)
        #pragma unroll
        for (int rg = 0; rg < 4; ++rg) acc[i][rg] = b2f(xv[i * 4 + rg]);
      if (t + 1 < TT) {
        const unsigned short* xw1 = xw_eco + (size_t)(t + 1) * 65536;
        #pragma unroll
        for (int i = 0; i < 16; ++i) xn[i] = xw1[xoff[i]];
      }
      #pragma unroll
      for (int kb = 0; kb < 8; ++kb) {
        bf16x8 a0 = *(const bf16x8*)&Hs[(kb * 32 + c) * 40 + grp * 8];
        bf16x8 a1 = *(const bf16x8*)&Hs[(kb * 32 + 16 + c) * 40 + grp * 8];
        bf16x8 b0 = *(const bf16x8*)&WR[(kb * 128 + w * 32 + c) * 40 + grp * 8];
        bf16x8 b1 = *(const bf16x8*)&WR[(kb * 128 + w * 32 + 16 + c) * 40 + grp * 8];
        acc[0] = __builtin_amdgcn_mfma_f32_16x16x32_bf16(a0, b0, acc[0], 0, 0, 0);
        acc[1] = __builtin_amdgcn_mfma_f32_16x16x32_bf16(a0, b1, acc[1], 0, 0, 0);
        acc[2] = __builtin_amdgcn_mfma_f32_16x16x32_bf16(a1, b0, acc[2], 0, 0, 0);
        acc[3] = __builtin_amdgcn_mfma_f32_16x16x32_bf16(a1, b1, acc[3], 0, 0, 0);
      }
      #pragma unroll
      for (int i = 0; i < 4; ++i) {
        int rt = i >> 1, ct = i & 1;
        #pragma unroll
        for (int rg = 0; rg < 4; ++rg)
          zsh[(rt * 16 + grp * 4 + rg) * 132 + w * 32 + ct * 16 + c] = acc[i][rg];
      }
      __syncthreads();
      { // cell update: 1 row x 4 hid, publish tagged pairs
        int row = tid >> 3, hq8 = tid & 7;
        float4 zi = *(const float4*)&zsh[row * 132 +      hq8 * 4];
        float4 zf = *(const float4*)&zsh[row * 132 + 32 + hq8 * 4];
        float4 zg = *(const float4*)&zsh[row * 132 + 64 + hq8 * 4];
        float4 zo = *(const float4*)&zsh[row * 132 + 96 + hq8 * 4];
        float4 c0 = *(const float4*)&cst[row * 32 + hq8 * 4];
        float cn0 = sigf(zf.x) * c0.x + sigf(zi.x) * tanh_(zg.x);
        float cn1 = sigf(zf.y) * c0.y + sigf(zi.y) * tanh_(zg.y);
        float cn2 = sigf(zf.z) * c0.z + sigf(zi.z) * tanh_(zg.z);
        float cn3 = sigf(zf.w) * c0.w + sigf(zi.w) * tanh_(zg.w);
        float hv0 = sigf(zo.x) * tanh_(cn0);
        float hv1 = sigf(zo.y) * tanh_(cn1);
        float hv2 = sigf(zo.z) * tanh_(cn2);
        float hv3 = sigf(zo.w) * tanh_(cn3);
        *(float4*)&cst[row * 32 + hq8 * 4] = make_float4(cn0, cn1, cn2, cn3);
        unsigned long long* ho = hE + (size_t)((t + 1) % RE) * 8192
                               + (bg * 32 + row) * 128 + wg * 16 + hq8 * 2;
        st64(&ho[0], tag2(t + 1, hv0, hv1));
        st64(&ho[1], tag2(t + 1, hv2, hv3));
      }
      // no trailing barrier: next step's Hs/zsh writes sit behind its own
      // barriers; cst is per-thread; publishes are tag-guarded.
      #pragma unroll
      for (int i = 0; i < 16; ++i) xv[i] = xn[i];
    }
  } else if (widx < 128) {
    // ================= rec1: data/att LSTM l1, 64 batch x 32 hid, xW fused
    unsigned short* WR = (unsigned short*)smem;             // 81920
    unsigned short* Hs = (unsigned short*)(smem + 81920);   // 40960
    float* zsh = (float*)(smem + 122880);                   // 33792
    float* a_sp = (float*)(smem + 156672);                  // 1024
    float* b_sp = (float*)(smem + 157696);                  // 2048
    float* bias_s = (float*)(smem + 159744);                // 512
    const int q = widx - 16, l1 = q >> 3, colwg = q & 7, br = l1 >> 1;
    const bool act_sig = (l1 & 1);
    const unsigned short* wr_g = wr_swz + ((size_t)(1 + l1) * 8 + colwg) * 32768;
    for (int i = tid * 8; i < 32768; i += 2048) {
      int kb = i >> 12; int rr = i & 4095; int col = rr >> 5; int ks = rr & 31;
      *(uint4*)&WR[(kb * 128 + col) * 40 + ks] = *(const uint4*)&wr_g[i];
    }
    bf16x8 wkf[16];
    const unsigned short* wk = wk_da + (size_t)l1 * 262144;
    #pragma unroll
    for (int kb = 0; kb < 8; ++kb)
      #pragma unroll
      for (int ct = 0; ct < 2; ++ct) {
        int col = w * 256 + colwg * 32 + ct * 16 + c;
        wkf[kb * 2 + ct] = *(const bf16x8*)&wk[kb * 32768 + col * 32 + grp * 8];
      }
    const float* spWk = (act_sig ? att_Wk : data_Wk) + (size_t)br * 266240;
    for (int i = tid; i < 512; i += 256) {
      int j = i >> 7, colL = i & 127;
      int gcol = (colL >> 5) * 256 + colwg * 32 + (colL & 31);
      b_sp[i] = spWk[(size_t)j * 1024 + gcol];
    }
    if (tid < 128) {
      int gcol = (tid >> 5) * 256 + colwg * 32 + (tid & 31);
      bias_s[tid] = (act_sig ? att_b : data_b)[br * 1024 + gcol];
    }
    float creg[8];
    #pragma unroll
    for (int j = 0; j < 8; ++j) creg[j] = 0.0f;
    unsigned long long* hDl = hD + (size_t)l1 * 2 * 8192;
    unsigned long long* ring = (act_sig ? hsA : hsD) + (size_t)br * RS * 8192;
    __syncthreads();

    for (int t = 0; t < TT; ++t) {
      // lagged ring guard: rec2 must have consumed the hs slot we overwrite
      if (t + 1 > RS && tid < 16) {
        while ((int)ld32(&h2f[br * 16 + tid]) < t + 1 - RS) __builtin_amdgcn_s_sleep(2);
      }
      if (tid < 64) {
        const float* ip = inputs + ((size_t)tid * TT + t) * 42;
        a_sp[tid * 4 + 0] = ip[20 + br];
        a_sp[tid * 4 + 1] = ip[27];
        a_sp[tid * 4 + 2] = ip[27 + br + 1];
        a_sp[tid * 4 + 3] = ip[27 + br + 8];
      }
      // issue both gathers
      const unsigned long long* he = hE + (size_t)((t + 1) % RE) * 8192;
      const unsigned long long* ho = hDl + (size_t)(t & 1) * 8192;
      unsigned long long ve[32], vh[32];
      #pragma unroll
      for (int i = 0; i < 32; ++i) ve[i] = ld64(&he[tid + i * 256]);
      #pragma unroll
      for (int i = 0; i < 32; ++i) vh[i] = ld64(&ho[tid + i * 256]);
      { // poll eco h tags == t+1
        const unsigned tagv = (unsigned)(t + 1);
        int tries = 0;
        while (true) {
          unsigned long long pend = 0ull;
          #pragma unroll
          for (int i = 0; i < 32; ++i)
            pend |= ((unsigned)(ve[i] >> 32) != tagv) ? (1ull << i) : 0ull;
          if (!pend) break;
          if (++tries > 8) __builtin_amdgcn_s_sleep(1);
          #pragma unroll
          for (int i = 0; i < 32; ++i)
            if (pend & (1ull << i)) ve[i] = ld64(&he[tid + i * 256]);
        }
      }
      #pragma unroll
      for (int i = 0; i < 32; ++i) {
        int m = tid + i * 256, row = m >> 7, kp = m & 127;
        *(unsigned int*)&Hs[((kp >> 4) * 64 + row) * 40 + 2 * (kp & 15)] = (unsigned int)ve[i];
      }
      __syncthreads();
      // xW MFMA (A = eco h, B = Wk regs)
      f32x4 acc[8] = {};
      #pragma unroll
      for (int kb = 0; kb < 8; ++kb) {
        bf16x8 a[4];
        #pragma unroll
        for (int rt = 0; rt < 4; ++rt)
          a[rt] = *(const bf16x8*)&Hs[(kb * 64 + rt * 16 + c) * 40 + grp * 8];
        #pragma unroll
        for (int rt = 0; rt < 4; ++rt)
          #pragma unroll
          for (int ct = 0; ct < 2; ++ct)
            acc[rt * 2 + ct] = __builtin_amdgcn_mfma_f32_16x16x32_bf16(a[rt], wkf[kb * 2 + ct], acc[rt * 2 + ct], 0, 0, 0);
      }
      #pragma unroll
      for (int i = 0; i < 8; ++i) {
        int rt = i >> 1, ct2 = i & 1;
        #pragma unroll
        for (int rg = 0; rg < 4; ++rg) {
          int row = rt * 16 + grp * 4 + rg;
          int colL = w * 32 + ct2 * 16 + c;
          acc[i][rg] += bias_s[colL]
                      + a_sp[row * 4 + 0] * b_sp[colL]       + a_sp[row * 4 + 1] * b_sp[128 + colL]
                      + a_sp[row * 4 + 2] * b_sp[256 + colL] + a_sp[row * 4 + 3] * b_sp[384 + colL];
        }
      }
      { // poll own h tags == t (usually instant)
        const unsigned tagv = (unsigned)t;
        int tries = 0;
        while (true) {
          unsigned long long pend = 0ull;
          #pragma unroll
          for (int i = 0; i < 32; ++i)
            pend |= ((unsigned)(vh[i] >> 32) != tagv) ? (1ull << i) : 0ull;
          if (!pend) break;
          if (++tries > 8) __builtin_amdgcn_s_sleep(1);
          #pragma unroll
          for (int i = 0; i < 32; ++i)
            if (pend & (1ull << i)) vh[i] = ld64(&ho[tid + i * 256]);
        }
      }
      __syncthreads();                 // everyone done reading Hs (eco h)
      #pragma unroll
      for (int i = 0; i < 32; ++i) {
        int m = tid + i * 256, row = m >> 7, kp = m & 127;
        *(unsigned int*)&Hs[((kp >> 4) * 64 + row) * 40 + 2 * (kp & 15)] = (unsigned int)vh[i];
      }
      __syncthreads();
      // recurrent MFMA (A = own h, B = Wr LDS)
      #pragma unroll
      for (int kb = 0; kb < 8; ++kb) {
        bf16x8 a[4]; bf16x8 b[2];
        #pragma unroll
        for (int rt = 0; rt < 4; ++rt)
          a[rt] = *(const bf16x8*)&Hs[(kb * 64 + rt * 16 + c) * 40 + grp * 8];
        #pragma unroll
        for (int ct = 0; ct < 2; ++ct)
          b[ct] = *(const bf16x8*)&WR[(kb * 128 + w * 32 + ct * 16 + c) * 40 + grp * 8];
        #pragma unroll
        for (int rt = 0; rt < 4; ++rt)
          #pragma unroll
          for (int ct = 0; ct < 2; ++ct)
            acc[rt * 2 + ct] = __builtin_amdgcn_mfma_f32_16x16x32_bf16(a[rt], b[ct], acc[rt * 2 + ct], 0, 0, 0);
      }
      #pragma unroll
      for (int i = 0; i < 8; ++i) {
        int rt = i >> 1, ct2 = i & 1;
        #pragma unroll
        for (int rg = 0; rg < 4; ++rg)
          zsh[(rt * 16 + grp * 4 + rg) * 132 + w * 32 + ct2 * 16 + c] = acc[i][rg];
      }
      __syncthreads();
      { // cell: 2 items x 4 hid; publish own h (2-slot) + hs ring (tag t+1)
        unsigned long long* hon = hDl + (size_t)((t + 1) & 1) * 8192;
        unsigned long long* rs = ring + (size_t)(t % RS) * 8192;
        #pragma unroll
        for (int it = 0; it < 2; ++it) {
          int m = tid + it * 256, row = m >> 3, hq8 = m & 7;
          float4 zi = *(const float4*)&zsh[row * 132 +      hq8 * 4];
          float4 zf = *(const float4*)&zsh[row * 132 + 32 + hq8 * 4];
          float4 zg = *(const float4*)&zsh[row * 132 + 64 + hq8 * 4];
          float4 zo = *(const float4*)&zsh[row * 132 + 96 + hq8 * 4];
          float g0 = act_sig ? sigf(zg.x) : tanh_(zg.x);
          float g1 = act_sig ? sigf(zg.y) : tanh_(zg.y);
          float g2 = act_sig ? sigf(zg.z) : tanh_(zg.z);
          float g3 = act_sig ? sigf(zg.w) : tanh_(zg.w);
          float cn0 = sigf(zf.x) * creg[it * 4 + 0] + sigf(zi.x) * g0;
          float cn1 = sigf(zf.y) * creg[it * 4 + 1] + sigf(zi.y) * g1;
          float cn2 = sigf(zf.z) * creg[it * 4 + 2] + sigf(zi.z) * g2;
          float cn3 = sigf(zf.w) * creg[it * 4 + 3] + sigf(zi.w) * g3;
          float hv0 = sigf(zo.x) * (act_sig ? sigf(cn0) : tanh_(cn0));
          float hv1 = sigf(zo.y) * (act_sig ? sigf(cn1) : tanh_(cn1));
          float hv2 = sigf(zo.z) * (act_sig ? sigf(cn2) : tanh_(cn2));
          float hv3 = sigf(zo.w) * (act_sig ? sigf(cn3) : tanh_(cn3));
          creg[it * 4 + 0] = cn0; creg[it * 4 + 1] = cn1;
          creg[it * 4 + 2] = cn2; creg[it * 4 + 3] = cn3;
          int kp = colwg * 16 + hq8 * 2;
          unsigned long long w0 = tag2(t + 1, hv0, hv1);
          unsigned long long w1 = tag2(t + 1, hv2, hv3);
          st64(&hon[row * 128 + kp], w0);
          st64(&hon[row * 128 + kp + 1], w1);
          st64(&rs[row * 128 + kp], w0);
          st64(&rs[row * 128 + kp + 1], w1);
        }
      }
      // no drain, no trailing barrier: stores flow out in background;
      // hDf only asserts hE-slot consumption (done at barrier #1).
      if (tid == 0) st32(&hDf[q], (unsigned)(t + 1));
    }
  } else {
    // ================= rec2: ts LSTM d, 32 batch x 32 hid, xW fused
    unsigned short* WR = (unsigned short*)smem;             // 81920
    unsigned short* Hs = (unsigned short*)(smem + 81920);   // 20480
    float* zsh = (float*)(smem + 102400);                   // 16896
    float* bias_s = (float*)(smem + 119296);                // 512
    const int r = widx - 128, d = r >> 4, sub = r & 15, colwg = sub >> 1, bg = sub & 1;
    const unsigned short* wr_g = wr_swz + ((size_t)(15 + d) * 8 + colwg) * 32768;
    for (int i = tid * 8; i < 32768; i += 2048) {
      int kb = i >> 12; int rr = i & 4095; int col = rr >> 5; int ks = rr & 31;
      *(uint4*)&WR[(kb * 128 + col) * 40 + ks] = *(const uint4*)&wr_g[i];
    }
    bf16x8 wkf[16];
    const unsigned short* wk = wk_ts + (size_t)d * 262144;
    #pragma unroll
    for (int kb = 0; kb < 8; ++kb)
      #pragma unroll
      for (int ct = 0; ct < 2; ++ct) {
        int col = w * 256 + colwg * 32 + ct * 16 + c;
        wkf[kb * 2 + ct] = *(const bf16x8*)&wk[kb * 32768 + col * 32 + grp * 8];
      }
    if (tid < 128) {
      int gcol = (tid >> 5) * 256 + colwg * 32 + (tid & 31);
      bias_s[tid] = ts_b[d * 1024 + gcol];
    }
    float creg[4] = {0.0f, 0.0f, 0.0f, 0.0f};
    const unsigned long long* rD = hsD + (size_t)d * RS * 8192;
    const unsigned long long* rA = hsA + (size_t)d * RS * 8192;
    unsigned long long* h2d = h2 + (size_t)d * 2 * 8192;
    __syncthreads();

    for (int t = 0; t < TT; ++t) {
      const unsigned long long* sd = rD + (size_t)(t % RS) * 8192;
      const unsigned long long* sa = rA + (size_t)(t % RS) * 8192;
      const unsigned long long* ho = h2d + (size_t)(t & 1) * 8192;
      unsigned long long vd[16], va[16], vh[16];
      int idx16[16];
      #pragma unroll
      for (int i = 0; i < 16; ++i) {
        int m = tid + i * 256;
        idx16[i] = (bg * 32 + (m >> 7)) * 128 + (m & 127);
      }
      #pragma unroll
      for (int i = 0; i < 16; ++i) vd[i] = ld64(&sd[idx16[i]]);
      #pragma unroll
      for (int i = 0; i < 16; ++i) va[i] = ld64(&sa[idx16[i]]);
      #pragma unroll
      for (int i = 0; i < 16; ++i) vh[i] = ld64(&ho[idx16[i]]);
      { // poll hs tags == t+1 (both rings)
        const unsigned tagv = (unsigned)(t + 1);
        int tries = 0;
        while (true) {
          unsigned pend = 0u;
          #pragma unroll
          for (int i = 0; i < 16; ++i) {
            pend |= ((unsigned)(vd[i] >> 32) != tagv) ? (1u << i) : 0u;
            pend |= ((unsigned)(va[i] >> 32) != tagv) ? (0x10000u << i) : 0u;
          }
          if (!pend) break;
          if (++tries > 8) __builtin_amdgcn_s_sleep(1);
          #pragma unroll
          for (int i = 0; i < 16; ++i) {
            if (pend & (1u << i)) vd[i] = ld64(&sd[idx16[i]]);
            if (pend & (0x10000u << i)) va[i] = ld64(&sa[idx16[i]]);
          }
        }
      }
      #pragma unroll
      for (int i = 0; i < 16; ++i) {  // product -> Hs
        int m = tid + i * 256, row = m >> 7, kp = m & 127;
        unsigned dl = (unsigned)vd[i], al = (unsigned)va[i];
        float p0 = b2f((unsigned short)dl) * b2f((unsigned short)al);
        float p1 = b2f((unsigned short)(dl >> 16)) * b2f((unsigned short)(al >> 16));
        unsigned pv = (unsigned)f2b(p0) | ((unsigned)f2b(p1) << 16);
        *(unsigned int*)&Hs[((kp >> 4) * 32 + row) * 40 + 2 * (kp & 15)] = pv;
      }
      __syncthreads();
      f32x4 acc[4] = {};
      #pragma unroll
      for (int kb = 0; kb < 8; ++kb) {
        bf16x8 a0 = *(const bf16x8*)&Hs[(kb * 32 + c) * 40 + grp * 8];
        bf16x8 a1 = *(const bf16x8*)&Hs[(kb * 32 + 16 + c) * 40 + grp * 8];
        acc[0] = __builtin_amdgcn_mfma_f32_16x16x32_bf16(a0, wkf[kb * 2 + 0], acc[0], 0, 0, 0);
        acc[1] = __builtin_amdgcn_mfma_f32_16x16x32_bf16(a0, wkf[kb * 2 + 1], acc[1], 0, 0, 0);
        acc[2] = __builtin_amdgcn_mfma_f32_16x16x32_bf16(a1, wkf[kb * 2 + 0], acc[2], 0, 0, 0);
        acc[3] = __builtin_amdgcn_mfma_f32_16x16x32_bf16(a1, wkf[kb * 2 + 1], acc[3], 0, 0, 0);
      }
      #pragma unroll
      for (int i = 0; i < 4; ++i) {
        int ct2 = i & 1;
        #pragma unroll
        for (int rg = 0; rg < 4; ++rg)
          acc[i][rg] += bias_s[w * 32 + ct2 * 16 + c];
      }
      { // poll own h tags == t (instant)
        const unsigned tagv = (unsigned)t;
        int tries = 0;
        while (true) {
          unsigned pend = 0u;
          #pragma unroll
          for (int i = 0; i < 16; ++i)
            pend |= ((unsigned)(vh[i] >> 32) != tagv) ? (1u << i) : 0u;
          if (!pend) break;
          if (++tries > 8) __builtin_amdgcn_s_sleep(1);
          #pragma unroll
          for (int i = 0; i < 16; ++i)
            if (pend & (1u << i)) vh[i] = ld64(&ho[idx16[i]]);
        }
      }
      __syncthreads();
      #pragma unroll
      for (int i = 0; i < 16; ++i) {
        int m = tid + i * 256, row = m >> 7, kp = m & 127;
        *(unsigned int*)&Hs[((kp >> 4) * 32 + row) * 40 + 2 * (kp & 15)] = (unsigned int)vh[i];
      }
      __syncthreads();
      #pragma unroll
      for (int kb = 0; kb < 8; ++kb) {
        bf16x8 a0 = *(const bf16x8*)&Hs[(kb * 32 + c) * 40 + grp * 8];
        bf16x8 a1 = *(const bf16x8*)&Hs[(kb * 32 + 16 + c) * 40 + grp * 8];
        bf16x8 b0 = *(const bf16x8*)&WR[(kb * 128 + w * 32 + c) * 40 + grp * 8];
        bf16x8 b1 = *(const bf16x8*)&WR[(kb * 128 + w * 32 + 16 + c) * 40 + grp * 8];
        acc[0] = __builtin_amdgcn_mfma_f32_16x16x32_bf16(a0, b0, acc[0], 0, 0, 0);
        acc[1] = __builtin_amdgcn_mfma_f32_16x16x32_bf16(a0, b1, acc[1], 0, 0, 0);
        acc[2] = __builtin_amdgcn_mfma_f32_16x16x32_bf16(a1, b0, acc[2], 0, 0, 0);
        acc[3] = __builtin_amdgcn_mfma_f32_16x16x32_bf16(a1, b1, acc[3], 0, 0, 0);
      }
      #pragma unroll
      for (int i = 0; i < 4; ++i) {
        int rt = i >> 1, ct2 = i & 1;
        #pragma unroll
        for (int rg = 0; rg < 4; ++rg)
          zsh[(rt * 16 + grp * 4 + rg) * 132 + w * 32 + ct2 * 16 + c] = acc[i][rg];
      }
      __syncthreads();
      { // cell: 1 row x 4 hid; publish h2 (2-slot)
        int row = tid >> 3, hq8 = tid & 7;
        float4 zi = *(const float4*)&zsh[row * 132 +      hq8 * 4];
        float4 zf = *(const float4*)&zsh[row * 132 + 32 + hq8 * 4];
        float4 zg = *(const float4*)&zsh[row * 132 + 64 + hq8 * 4];
        float4 zo = *(const float4*)&zsh[row * 132 + 96 + hq8 * 4];
        float cn0 = sigf(zf.x) * creg[0] + sigf(zi.x) * tanh_(zg.x);
        float cn1 = sigf(zf.y) * creg[1] + sigf(zi.y) * tanh_(zg.y);
        float cn2 = sigf(zf.z) * creg[2] + sigf(zi.z) * tanh_(zg.z);
        float cn3 = sigf(zf.w) * creg[3] + sigf(zi.w) * tanh_(zg.w);
        float hv0 = sigf(zo.x) * tanh_(cn0);
        float hv1 = sigf(zo.y) * tanh_(cn1);
        float hv2 = sigf(zo.z) * tanh_(cn2);
        float hv3 = sigf(zo.w) * tanh_(cn3);
        creg[0] = cn0; creg[1] = cn1; creg[2] = cn2; creg[3] = cn3;
        unsigned long long* hn = h2d + (size_t)((t + 1) & 1) * 8192
                               + (bg * 32 + row) * 128 + colwg * 16 + hq8 * 2;
        st64(&hn[0], tag2(t + 1, hv0, hv1));
        st64(&hn[1], tag2(t + 1, hv2, hv3));
        if (t == TT - 1) {
          *(float4*)&h_last[(size_t)d * 16384 + (bg * 32 + row) * 256 + colwg * 32 + hq8 * 4]
              = make_float4(hv0, hv1, hv2, hv3);
        }
      }
      // no drain, no trailing barrier: h2f only asserts hs-ring consumption
      // (done at barrier #1); publishes are tag-guarded.
      if (tid == 0) st32(&h2f[d * 16 + sub], (unsigned)(t + 1));
    }
  }
}

// ------------------------------------------------ head
__global__ __launch_bounds__(256) void k7_d1(const float* __restrict__ h_last,
    const float* __restrict__ d1_W, const float* __restrict__ d1_b, float* __restrict__ d1o)
{
  __shared__ float Asl[64 * 256];
  __shared__ float Bsl[256 * 64];
  const int nt = blockIdx.x, br = blockIdx.y, tid = threadIdx.x;
  const float* hl = h_last + (size_t)br * 16384;
  for (int i = tid; i < 16384; i += 256) Asl[i] = hl[i];
  const float* wp = d1_W + (size_t)br * 65536 + nt * 64;
  for (int i = tid; i < 16384; i += 256) {
    int k = i >> 6, cl = i & 63;
    Bsl[i] = wp[(size_t)k * 256 + cl];
  }
  __syncthreads();
  const int cl = tid & 63, rq = tid >> 6;
  float s[16];
  const float bias = d1_b[br * 256 + nt * 64 + cl];
  #pragma unroll
  for (int i = 0; i < 16; ++i) s[i] = bias;
  for (int k = 0; k < 256; ++k) {
    float bv = Bsl[k * 64 + cl];
    #pragma unroll
    for (int i = 0; i < 16; ++i) s[i] += Asl[(rq * 16 + i) * 256 + k] * bv;
  }
  #pragma unroll
  for (int i = 0; i < 16; ++i)
    d1o[(size_t)br * 16384 + (rq * 16 + i) * 256 + nt * 64 + cl] = fmaxf(s[i], 0.0f);
}

__global__ __launch_bounds__(256) void k8_head(const float* __restrict__ d1o,
    const float* __restrict__ d2_W, const float* __restrict__ d2_b,
    const float* __restrict__ df_W, const float* __restrict__ df_b,
    const float* __restrict__ inputs, float* __restrict__ out)
{
  __shared__ float Asl[64 * 256];
  __shared__ float Bsl[256 * 64];
  __shared__ float d2sT[64 * 65];
  __shared__ float wfs[68];
  const int br = blockIdx.x, tid = threadIdx.x;
  for (int i = tid; i < 16384; i += 256) Asl[i] = d1o[(size_t)br * 16384 + i];
  for (int i = tid; i < 16384; i += 256) Bsl[i] = d2_W[(size_t)br * 16384 + i];
  if (tid < 67) wfs[tid] = df_W[br * 67 + tid];
  __syncthreads();
  const int cl = tid & 63, rq = tid >> 6;
  float s[16];
  const float bias = d2_b[br * 64 + cl];
  #pragma unroll
  for (int i = 0; i < 16; ++i) s[i] = bias;
  for (int k = 0; k < 256; ++k) {
    float bv = Bsl[k * 64 + cl];
    #pragma unroll
    for (int i = 0; i < 16; ++i) s[i] += Asl[(rq * 16 + i) * 256 + k] * bv;
  }
  #pragma unroll
  for (int i = 0; i < 16; ++i) d2sT[cl * 65 + rq * 16 + i] = fmaxf(s[i], 0.0f);
  __syncthreads();
  if (tid < 64) {
    const int b = tid;
    const float* ip = inputs + ((size_t)b * TT + (TT - 1)) * 42;
    float acc = df_b[br] + ip[20 + br] + ip[27] * wfs[64] + ip[27 + br + 1] * wfs[65]
              + ip[27 + br + 8] * wfs[66];
    #pragma unroll 4
    for (int j = 0; j < 64; ++j) acc += d2sT[j * 65 + b] * wfs[j];
    out[b * 7 + br] = acc;
  }
}

// ------------------------------------------------ host
extern "C" void kernel_launch(void* const* d_in, const int* in_sizes, int n_in,
                              void* d_out, int out_size, void* d_ws, size_t ws_size,
                              hipStream_t stream) {
  (void)in_sizes; (void)n_in; (void)out_size;
  const float* inputs  = (const float*)d_in[0];
  const float* eco_Wk  = (const float*)d_in[1];
  const float* eco_Wr  = (const float*)d_in[2];
  const float* eco_b   = (const float*)d_in[3];
  const float* data_Wk = (const float*)d_in[4];
  const float* data_Wr = (const float*)d_in[5];
  const float* data_b  = (const float*)d_in[6];
  const float* att_Wk  = (const float*)d_in[7];
  const float* att_Wr  = (const float*)d_in[8];
  const float* att_b   = (const float*)d_in[9];
  const float* ts_Wk   = (const float*)d_in[10];
  const float* ts_Wr   = (const float*)d_in[11];
  const float* ts_b    = (const float*)d_in[12];
  const float* d1_W    = (const float*)d_in[13];
  const float* d1_b    = (const float*)d_in[14];
  const float* d2_W    = (const float*)d_in[15];
  const float* d2_b    = (const float*)d_in[16];
  const float* df_W    = (const float*)d_in[17];
  const float* df_b    = (const float*)d_in[18];

  char* ws = (char*)d_ws;
  size_t off = 0;
  auto take = [&](size_t bytes) -> void* {
    void* p = ws + off;
    off += (bytes + 255) & ~(size_t)255;
    return p;
  };
  unsigned short* wr_swz = (unsigned short*)take((size_t)22 * 262144 * 2);
  unsigned short* wk_da  = (unsigned short*)take((size_t)14 * 262144 * 2);
  unsigned short* wk_ts  = (unsigned short*)take((size_t)7  * 262144 * 2);
  unsigned short* xw_eco = (unsigned short*)take((size_t)TT * 65536 * 2);
  float*          h_last = (float*)take((size_t)7 * 16384 * 4);
  float*          d1o    = (float*)take((size_t)7 * 16384 * 4);
  // --- sync region (contiguous, memset each launch) ---
  size_t sync_begin = off;
  unsigned long long* hE  = (unsigned long long*)take((size_t)RE * 8192 * 8);
  unsigned long long* hD  = (unsigned long long*)take((size_t)14 * 2 * 8192 * 8);
  unsigned long long* hsD = (unsigned long long*)take((size_t)7 * RS * 8192 * 8);
  unsigned long long* hsA = (unsigned long long*)take((size_t)7 * RS * 8192 * 8);
  unsigned long long* h2  = (unsigned long long*)take((size_t)7 * 2 * 8192 * 8);
  unsigned* hDf = (unsigned*)take(112 * 4);
  unsigned* h2f = (unsigned*)take(112 * 4);
  size_t sync_bytes = off - sync_begin;
  if (off > ws_size) return;   // fail loudly (output stays zero)

  hipMemsetAsync(ws + sync_begin, 0, sync_bytes, stream);
  k0a_wr<<<dim3(8, 8, 22), 256, 0, stream>>>(eco_Wr, data_Wr, att_Wr, ts_Wr, wr_swz);
  k0b_wk<<<dim3(4, 8, 21), 256, 0, stream>>>(data_Wk, att_Wk, ts_Wk, wk_da, wk_ts);
  k1_ecoxw<<<dim3(TT, 4), 256, 0, stream>>>(inputs, eco_Wk, eco_b, xw_eco);
  kP<<<240, 256, 0, stream>>>(wr_swz, wk_da, wk_ts, xw_eco, inputs,
                              data_Wk, att_Wk, data_b, att_b, ts_b,
                              hE, hD, hsD, hsA, h2, hDf, h2f, h_last);
  k7_d1<<<dim3(4, 7), 256, 0, stream>>>(h_last, d1_W, d1_b, d1o);
  k8_head<<<7, 256, 0, stream>>>(d1o, d2_W, d2_b, df_W, df_b, inputs, (float*)d_out);
}